// Round 6
// baseline (172.784 us; speedup 1.0000x reference)
//
#include <hip/hip_runtime.h>

typedef __attribute__((ext_vector_type(8))) short short8;
typedef __attribute__((ext_vector_type(4))) float f32x4;

#define BB 64      // batch
#define CC 256     // query dim
#define DD 128     // key/value dim
#define NN 100000  // bank entries
#define KK 8       // top-k

#define CHUNK 128                         // keys per block (kernel B)
#define NBLK ((NN + CHUNK - 1) / CHUNK)   // 782
#define CPB (NBLK * KK)                   // candidates per row = 6256

// f32 -> bf16 bits, round-nearest-even
__device__ __forceinline__ unsigned short f2bf(float x) {
    unsigned u = __float_as_uint(x);
    unsigned r = u + 0x7fffu + ((u >> 16) & 1u);
    return (unsigned short)(r >> 16);
}

// split x into bf16 hi + bf16 lo (RNE, x ~= hi + lo)
__device__ __forceinline__ void split_bf(float x, unsigned short& h, unsigned short& l) {
    h = f2bf(x);
    float hf = __uint_as_float(((unsigned)h) << 16);
    l = f2bf(x - hf);
}

// branchless sorted-descending top-8 insert, floats only (16 VALU, no branches)
__device__ __forceinline__ void bfins8(float x, float l[8]) {
#pragma unroll
    for (int s = 0; s < 8; ++s) {
        float hi = fmaxf(l[s], x);
        x = fminf(l[s], x);
        l[s] = hi;
    }
}

// branchless sorted-descending top-8 insert, (value,index) pairs
__device__ __forceinline__ void bpins8(float v, int ix, float lv[8], int li[8]) {
#pragma unroll
    for (int s = 0; s < 8; ++s) {
        const bool gt = v > lv[s];
        const float nv = gt ? lv[s] : v;
        const int   ni = gt ? li[s] : ix;
        lv[s] = gt ? v : lv[s];
        li[s] = gt ? ix : li[s];
        v = nv; ix = ni;
    }
}

// top-8 of two sorted-desc 8-lists, result sorted desc.
// c[i] = max(a[i], b[7-i]) is a bitonic (valley) sequence -> 12-CE bitonic sort.
__device__ __forceinline__ void merge8(const float a[8], const float b[8], float o[8]) {
    float m[8];
#pragma unroll
    for (int i = 0; i < 8; ++i) m[i] = fmaxf(a[i], b[7 - i]);
#define CE(i, j) { float hi = fmaxf(m[i], m[j]); float lo = fminf(m[i], m[j]); m[i] = hi; m[j] = lo; }
    CE(0, 4) CE(1, 5) CE(2, 6) CE(3, 7)
    CE(0, 2) CE(1, 3) CE(4, 6) CE(5, 7)
    CE(0, 1) CE(2, 3) CE(4, 5) CE(6, 7)
#undef CE
#pragma unroll
    for (int i = 0; i < 8; ++i) o[i] = m[i];
}

// ---------------- Kernel A: q = query @ Wq^T + bq -> bf16 hi/lo A-fragments ----
// (row l2-norm dropped: per-row scale cannot change that row's top-k)
__global__ __launch_bounds__(128) void qproj_kernel(
    const float* __restrict__ query,  // [64][256]
    const float* __restrict__ Wq,     // [128][256]
    const float* __restrict__ bq,     // [128]
    unsigned short* __restrict__ qAhi, // [8192] fragment-ordered
    unsigned short* __restrict__ qAlo) // [8192]
{
    __shared__ float qrow[CC];
    const int tid = threadIdx.x;   // = d
    const int b = blockIdx.x;
    for (int i = tid; i < CC; i += 128) qrow[i] = query[b * CC + i];
    __syncthreads();
    float acc = bq[tid];
    const float4* wr = reinterpret_cast<const float4*>(Wq + (size_t)tid * CC);
#pragma unroll 8
    for (int c = 0; c < CC / 4; ++c) {
        float4 w = wr[c];
        acc = fmaf(w.x, qrow[c * 4 + 0], acc);
        acc = fmaf(w.y, qrow[c * 4 + 1], acc);
        acc = fmaf(w.z, qrow[c * 4 + 2], acc);
        acc = fmaf(w.w, qrow[c * 4 + 3], acc);
    }
    unsigned short h, l;
    split_bf(acc, h, l);
    // A-frag (16x16x32): lane holds A[m=lane&15][k=(lane>>4)*8+j]
    const int d = tid;
    const int mt = b >> 4, n = b & 15;
    const int ks = d >> 5, quad = (d >> 3) & 3, j = d & 7;
    const size_t fi = ((size_t)(mt * 4 + ks) * 64 + quad * 16 + n) * 8 + j;
    qAhi[fi] = h;
    qAlo[fi] = l;
}

// ---------------- Kernel B: bf16x3 MFMA sim + per-chunk top-8 (packed-float) ---
// 256 threads / 4 waves, 5 blocks/CU (32 KB LDS, VGPR capped 102).
// Wave (p=w>>1, h=w&1): rows p*32..+31, keys key0+h*64..+63 (4 N-tiles of 16).
// sims stored XOR-swizzled: phys = row*128 + (jl ^ ((row&4)<<2)) -> all LDS
// access phases exactly 2-way (free). Low 7 mantissa bits of each sim hold the
// within-block key idx; chunk id is implicit in the candidate position.
__global__ __launch_bounds__(256, 5) void simtopk_kernel(
    const unsigned short* __restrict__ qAhi,
    const unsigned short* __restrict__ qAlo,
    const float* __restrict__ keys,   // [N][128]
    const float* __restrict__ imp,    // [N]
    float* __restrict__ cand_v)       // [64][CPB] packed floats
{
    __shared__ float sims[64 * 128];  // 32768 B exactly (sims; then lists)

    const int tid = threadIdx.x;
    const int w = tid >> 6, lane = tid & 63;
    const int p = w >> 1;          // row-pair group
    const int h = w & 1;           // key half
    const int blk = blockIdx.x;
    const int key0 = blk * CHUNK;
    const int n = lane & 15, quad = lane >> 4;

    // ---- A fragments straight from global (L2/L3-hot, shared by all blocks) ----
    short8 Ah[2][4], Al[2][4];
    {
        const short8* GH = reinterpret_cast<const short8*>(qAhi);
        const short8* GL = reinterpret_cast<const short8*>(qAlo);
#pragma unroll
        for (int m2 = 0; m2 < 2; ++m2)
#pragma unroll
            for (int ks = 0; ks < 4; ++ks) {
                const int idx = ((p * 2 + m2) * 4 + ks) * 64 + lane;
                Ah[m2][ks] = GH[idx];
                Al[m2][ks] = GL[idx];
            }
    }

    // ---- 4 N-tiles of 16 keys ----
#pragma unroll
    for (int t = 0; t < 4; ++t) {
        const int jl = h * 64 + t * 16 + n;
        const int j = key0 + jl;
        const int jc = (j < NN) ? j : (NN - 1);
        const float* kb = keys + (size_t)jc * DD + quad * 8;

        f32x4 acc[2];
        acc[0] = (f32x4){0.f, 0.f, 0.f, 0.f};
        acc[1] = (f32x4){0.f, 0.f, 0.f, 0.f};
        float ss = 0.f;

#pragma unroll
        for (int ks = 0; ks < 4; ++ks) {
            const float4 b0 = *reinterpret_cast<const float4*>(kb + ks * 32);
            const float4 b1 = *reinterpret_cast<const float4*>(kb + ks * 32 + 4);
            const float f[8] = {b0.x, b0.y, b0.z, b0.w, b1.x, b1.y, b1.z, b1.w};
            unsigned hw[4], lw[4];
#pragma unroll
            for (int e = 0; e < 4; ++e) {
                const float f0 = f[2 * e], f1 = f[2 * e + 1];
                const unsigned u0 = __float_as_uint(f0), u1 = __float_as_uint(f1);
                hw[e] = __builtin_amdgcn_perm(u1, u0, 0x07060302u);
                const float d0 = f0 - __uint_as_float(u0 & 0xffff0000u);
                const float d1 = f1 - __uint_as_float(u1 & 0xffff0000u);
                lw[e] = __builtin_amdgcn_perm(__float_as_uint(d1), __float_as_uint(d0), 0x07060302u);
                ss = fmaf(f0, f0, fmaf(f1, f1, ss));
            }
            uint4 hv = {hw[0], hw[1], hw[2], hw[3]};
            uint4 lv = {lw[0], lw[1], lw[2], lw[3]};
            short8 Bh = *reinterpret_cast<short8*>(&hv);
            short8 Bl = *reinterpret_cast<short8*>(&lv);
#pragma unroll
            for (int m2 = 0; m2 < 2; ++m2) {
                acc[m2] = __builtin_amdgcn_mfma_f32_16x16x32_bf16(Ah[m2][ks], Bh, acc[m2], 0, 0, 0);
                acc[m2] = __builtin_amdgcn_mfma_f32_16x16x32_bf16(Ah[m2][ks], Bl, acc[m2], 0, 0, 0);
                acc[m2] = __builtin_amdgcn_mfma_f32_16x16x32_bf16(Al[m2][ks], Bh, acc[m2], 0, 0, 0);
            }
        }

        // key norm: lane holds 32 of 128 elems; reduce across quads
        ss += __shfl_xor(ss, 16);
        ss += __shfl_xor(ss, 32);
        const bool valid = (j < NN);
        float scale = 0.f;
        if (valid) scale = imp[j] / fmaxf(sqrtf(ss), 1e-12f);

        // D layout: col = lane&15 (key), row = quad*4 + reg (+ m-tile*16)
        // swizzled store: phys = row*128 + (jl ^ ((row&4)<<2))  [exactly 2-way]
#pragma unroll
        for (int m2 = 0; m2 < 2; ++m2)
#pragma unroll
            for (int r = 0; r < 4; ++r) {
                const int row = (p * 2 + m2) * 16 + quad * 4 + r;
                const float v = valid ? acc[m2][r] * scale : -1e30f;
                const unsigned packed = (__float_as_uint(v) & ~0x7Fu) | (unsigned)jl;
                sims[row * 128 + (jl ^ ((row & 4) << 2))] = __uint_as_float(packed);
            }
    }
    __syncthreads();

    // ---- S1: 4 threads/row scan 32 phys slots each, order i^(row&15)^(8p)
    //      -> bank = i ^ (row&15) ^ 8p : exactly 2-way (free). Any scan order
    //      is valid: key identity is packed inside the value.
    float v8[8];
    {
        const int row = tid >> 2, part = tid & 3;
#pragma unroll
        for (int s = 0; s < 8; ++s) v8[s] = -1e30f;
        const float* rp = &sims[row * 128 + part * 32];
        const int sc = (row & 15) ^ (part << 3);
        for (int i = 0; i < 32; ++i)
            bfins8(rp[(i ^ sc) & 31], v8);
    }
    __syncthreads();   // all S1 reads complete; sims region reusable

    // ---- write sorted partial lists, rotated: slot=(4s+p+4(row&7))&31 [2-way] --
    {
        const int row = tid >> 2, part = tid & 3;
        const int rot = (row & 7) * 4;
#pragma unroll
        for (int s = 0; s < 8; ++s)
            sims[row * 128 + ((4 * s + part + rot) & 31)] = v8[s];
    }
    __syncthreads();

    // ---- S2: 1 thread/row, bitonic-merge 4 sorted lists -> top-8, write ----
    if (tid < 64) {
        const int row = tid;
        const int rot = (row & 7) * 4;
        float l0[8], l1[8], l2[8], l3[8];
#pragma unroll
        for (int s = 0; s < 8; ++s) {
            const float* rp = &sims[row * 128];
            l0[s] = rp[(4 * s + 0 + rot) & 31];
            l1[s] = rp[(4 * s + 1 + rot) & 31];
            l2[s] = rp[(4 * s + 2 + rot) & 31];
            l3[s] = rp[(4 * s + 3 + rot) & 31];
        }
        float m01[8], m23[8], m8[8];
        merge8(l0, l1, m01);
        merge8(l2, l3, m23);
        merge8(m01, m23, m8);
        float4* out4 = reinterpret_cast<float4*>(cand_v + (size_t)row * CPB + (size_t)blk * KK);
        out4[0] = (float4){m8[0], m8[1], m8[2], m8[3]};
        out4[1] = (float4){m8[4], m8[5], m8[6], m8[7]};
    }
}

// ---------------- Kernel CD: per-row candidate merge + attention + W_comb -----
__global__ __launch_bounds__(256) void mergefinish_kernel(
    const float* __restrict__ cand_v,  // [64][CPB] packed floats
    const float* __restrict__ values,  // [N][128]
    const float* __restrict__ w_attn,  // [128]
    const float* __restrict__ b_attn,  // [1]
    const float* __restrict__ W_comb,  // [128][128]
    const float* __restrict__ b_comb,  // [128]
    float* __restrict__ out)           // [64][128]
{
    __shared__ float lv[256 * 8];
    __shared__ int   li[256 * 8];
    __shared__ int   tk[KK];
    __shared__ float red[KK][DD];
    __shared__ float tvals[KK];
    __shared__ float mem[DD];

    const int tid = threadIdx.x;
    const int row = blockIdx.x;

    // P1: 256 threads scan the row's 6256 candidates (float4, coalesced)
    {
        float v8[8]; int i8[8];
#pragma unroll
        for (int s = 0; s < 8; ++s) { v8[s] = -1e30f; i8[s] = 0; }
        const float4* cv4 = reinterpret_cast<const float4*>(cand_v + (size_t)row * CPB);
        for (int c4 = tid; c4 < CPB / 4; c4 += 256) {
            const float4 v = cv4[c4];
            const int c = c4 * 4;
            bpins8(v.x, c + 0, v8, i8);
            bpins8(v.y, c + 1, v8, i8);
            bpins8(v.z, c + 2, v8, i8);
            bpins8(v.w, c + 3, v8, i8);
        }
#pragma unroll
        for (int s = 0; s < 8; ++s) { lv[tid * 8 + s] = v8[s]; li[tid * 8 + s] = i8[s]; }
    }
    __syncthreads();

    // P2: wave 0 reduces 256 lists -> 64 lists -> top-8 via head extraction.
    // Candidate position c decodes to key idx: (c>>3)*CHUNK + (bits(v)&127).
    if (tid < 64) {
        float m8[8]; int mi8[8];
#pragma unroll
        for (int s = 0; s < 8; ++s) { m8[s] = -1e30f; mi8[s] = 0; }
        for (int k2 = 0; k2 < 4; ++k2)
#pragma unroll
            for (int s = 0; s < 8; ++s)
                bpins8(lv[(tid + 64 * k2) * 8 + s], li[(tid + 64 * k2) * 8 + s], m8, mi8);
        for (int rd = 0; rd < KK; ++rd) {
            float m = m8[0];
#pragma unroll
            for (int d = 1; d < 64; d <<= 1) m = fmaxf(m, __shfl_xor(m, d));
            const unsigned long long msk = __ballot(m8[0] == m);
            const int wl = (int)(__ffsll((long long)msk) - 1);
            const int wc = __shfl(mi8[0], wl);
            if (tid == 0)
                tk[rd] = (wc >> 3) * CHUNK + (int)(__float_as_uint(m) & 127u);
            if (tid == wl) {
#pragma unroll
                for (int s = 0; s < 7; ++s) { m8[s] = m8[s + 1]; mi8[s] = mi8[s + 1]; }
                m8[7] = -1e30f;
            }
        }
    }
    __syncthreads();

    // D phase: gather + softmax attention + W_comb (threads 0..127 active)
    float vk[KK];
    if (tid < 128) {
#pragma unroll
        for (int k = 0; k < KK; ++k)
            vk[k] = values[(size_t)tk[k] * DD + tid];
        const float wa = w_attn[tid];
#pragma unroll
        for (int k = 0; k < KK; ++k) red[k][tid] = vk[k] * wa;
    }
    __syncthreads();
    if (tid < KK) {
        float s = 0.f;
        for (int i = 0; i < DD; ++i) s += red[tid][i];
        tvals[tid] = s + b_attn[0];
    }
    __syncthreads();
    if (tid < 128) {
        float m = tvals[0];
#pragma unroll
        for (int k = 1; k < KK; ++k) m = fmaxf(m, tvals[k]);
        float e[KK]; float se = 0.f;
#pragma unroll
        for (int k = 0; k < KK; ++k) { e[k] = expf(tvals[k] - m); se += e[k]; }
        const float inv = 1.f / se;
        float md = 0.f;
#pragma unroll
        for (int k = 0; k < KK; ++k) md += (e[k] * inv) * vk[k];
        mem[tid] = md;
    }
    __syncthreads();
    if (tid < 128) {
        float acc = b_comb[tid];
        const float4* wrow = reinterpret_cast<const float4*>(W_comb + (size_t)tid * DD);
#pragma unroll 8
        for (int c = 0; c < DD / 4; ++c) {
            float4 wv = wrow[c];
            acc = fmaf(wv.x, mem[c * 4 + 0], acc);
            acc = fmaf(wv.y, mem[c * 4 + 1], acc);
            acc = fmaf(wv.z, mem[c * 4 + 2], acc);
            acc = fmaf(wv.w, mem[c * 4 + 3], acc);
        }
        out[row * DD + tid] = acc;
    }
}

extern "C" void kernel_launch(void* const* d_in, const int* in_sizes, int n_in,
                              void* d_out, int out_size, void* d_ws, size_t ws_size,
                              hipStream_t stream) {
    const float* query  = (const float*)d_in[0];
    const float* keys   = (const float*)d_in[1];
    const float* values = (const float*)d_in[2];
    const float* imp    = (const float*)d_in[3];
    const float* Wq     = (const float*)d_in[4];
    const float* bq     = (const float*)d_in[5];
    const float* wattn  = (const float*)d_in[6];
    const float* battn  = (const float*)d_in[7];
    const float* Wcomb  = (const float*)d_in[8];
    const float* bcomb  = (const float*)d_in[9];

    unsigned short* qAhi = (unsigned short*)d_ws;          // 8192 ushort (16 KB)
    unsigned short* qAlo = qAhi + 8192;                    // 8192 ushort (16 KB)
    float* cand_v = (float*)(qAlo + 8192);                 // 64*CPB floats (1.6 MB)

    qproj_kernel<<<BB, 128, 0, stream>>>(query, Wq, bq, qAhi, qAlo);
    simtopk_kernel<<<NBLK, 256, 0, stream>>>(qAhi, qAlo, keys, imp, cand_v);
    mergefinish_kernel<<<BB, 256, 0, stream>>>(cand_v, values, wattn, battn,
                                               Wcomb, bcomb, (float*)d_out);
}

// Round 7
// 162.959 us; speedup vs baseline: 1.0603x; 1.0603x over previous
//
#include <hip/hip_runtime.h>

typedef __attribute__((ext_vector_type(8))) short short8;
typedef __attribute__((ext_vector_type(4))) float f32x4;

#define BB 64      // batch
#define CC 256     // query dim
#define DD 128     // key/value dim
#define NN 100000  // bank entries
#define KK 8       // top-k

#define CHUNK 128                         // keys per block (kernel B)
#define NBLK ((NN + CHUNK - 1) / CHUNK)   // 782
#define CPB (NBLK * KK)                   // candidates per row = 6256

// f32 -> bf16 bits, round-nearest-even
__device__ __forceinline__ unsigned short f2bf(float x) {
    unsigned u = __float_as_uint(x);
    unsigned r = u + 0x7fffu + ((u >> 16) & 1u);
    return (unsigned short)(r >> 16);
}

// split x into bf16 hi + bf16 lo (RNE, x ~= hi + lo)
__device__ __forceinline__ void split_bf(float x, unsigned short& h, unsigned short& l) {
    h = f2bf(x);
    float hf = __uint_as_float(((unsigned)h) << 16);
    l = f2bf(x - hf);
}

// branchless sorted-descending top-8 insert, (value,index) pairs
__device__ __forceinline__ void bpins8(float v, int ix, float lv[8], int li[8]) {
#pragma unroll
    for (int s = 0; s < 8; ++s) {
        const bool gt = v > lv[s];
        const float nv = gt ? lv[s] : v;
        const int   ni = gt ? li[s] : ix;
        lv[s] = gt ? v : lv[s];
        li[s] = gt ? ix : li[s];
        v = nv; ix = ni;
    }
}

#define CE(i, j) { float hi = fmaxf(m[i], m[j]); float lo = fminf(m[i], m[j]); m[i] = hi; m[j] = lo; }

// Batcher odd-even mergesort, 8 elements, descending, 19 CE
__device__ __forceinline__ void sort8(float m[8]) {
    CE(0, 1) CE(2, 3) CE(4, 5) CE(6, 7)
    CE(0, 2) CE(1, 3) CE(4, 6) CE(5, 7)
    CE(1, 2) CE(5, 6)
    CE(0, 4) CE(1, 5) CE(2, 6) CE(3, 7)
    CE(2, 4) CE(3, 5)
    CE(1, 2) CE(3, 4) CE(5, 6)
}

// top-8 of two sorted-desc 8-lists, result sorted desc.
// m[i] = max(a[i], b[7-i]) is bitonic -> 12-CE bitonic cleanup.
__device__ __forceinline__ void merge8(const float a[8], const float b[8], float o[8]) {
    float m[8];
#pragma unroll
    for (int i = 0; i < 8; ++i) m[i] = fmaxf(a[i], b[7 - i]);
    CE(0, 4) CE(1, 5) CE(2, 6) CE(3, 7)
    CE(0, 2) CE(1, 3) CE(4, 6) CE(5, 7)
    CE(0, 1) CE(2, 3) CE(4, 5) CE(6, 7)
#pragma unroll
    for (int i = 0; i < 8; ++i) o[i] = m[i];
}
#undef CE

// ---------------- Kernel A: q = query @ Wq^T + bq -> bf16 hi/lo A-fragments ----
// (row l2-norm dropped: per-row scale cannot change that row's top-k)
__global__ __launch_bounds__(128) void qproj_kernel(
    const float* __restrict__ query,  // [64][256]
    const float* __restrict__ Wq,     // [128][256]
    const float* __restrict__ bq,     // [128]
    unsigned short* __restrict__ qAhi, // [8192] fragment-ordered
    unsigned short* __restrict__ qAlo) // [8192]
{
    __shared__ float qrow[CC];
    const int tid = threadIdx.x;   // = d
    const int b = blockIdx.x;
    for (int i = tid; i < CC; i += 128) qrow[i] = query[b * CC + i];
    __syncthreads();
    float acc = bq[tid];
    const float4* wr = reinterpret_cast<const float4*>(Wq + (size_t)tid * CC);
#pragma unroll 8
    for (int c = 0; c < CC / 4; ++c) {
        float4 w = wr[c];
        acc = fmaf(w.x, qrow[c * 4 + 0], acc);
        acc = fmaf(w.y, qrow[c * 4 + 1], acc);
        acc = fmaf(w.z, qrow[c * 4 + 2], acc);
        acc = fmaf(w.w, qrow[c * 4 + 3], acc);
    }
    unsigned short h, l;
    split_bf(acc, h, l);
    // A-frag (16x16x32): lane holds A[m=lane&15][k=(lane>>4)*8+j]
    const int d = tid;
    const int mt = b >> 4, n = b & 15;
    const int ks = d >> 5, quad = (d >> 3) & 3, j = d & 7;
    const size_t fi = ((size_t)(mt * 4 + ks) * 64 + quad * 16 + n) * 8 + j;
    qAhi[fi] = h;
    qAlo[fi] = l;
}

// ---------------- Kernel B: bf16x3 MFMA sim + per-chunk top-8 (packed-float) ---
// 256 threads / 4 waves, 4 blocks/CU (grid 782 ~= 3/CU: fully co-resident).
// Wave (p=w>>1, h=w&1): rows p*32..+31, keys key0+h*64..+63 (4 N-tiles of 16).
// A-frags direct from global (L2). B-frags from global f32 keys, trunc-split
// to bf16 hi/lo. sims packed: low 7 mantissa bits hold the within-block key
// idx; chunk id is implicit in the candidate position (cand_i eliminated).
__global__ __launch_bounds__(256, 4) void simtopk_kernel(
    const unsigned short* __restrict__ qAhi,
    const unsigned short* __restrict__ qAlo,
    const float* __restrict__ keys,   // [N][128]
    const float* __restrict__ imp,    // [N]
    float* __restrict__ cand_v)       // [64][CPB] packed floats
{
    __shared__ float sims[64 * 132];  // 33792 B (sims; then partial lists)

    const int tid = threadIdx.x;
    const int w = tid >> 6, lane = tid & 63;
    const int p = w >> 1;          // row-pair group
    const int h = w & 1;           // key half
    const int blk = blockIdx.x;
    const int key0 = blk * CHUNK;
    const int n = lane & 15, quad = lane >> 4;

    // ---- A fragments straight from global ----
    short8 Ah[2][4], Al[2][4];
    {
        const short8* GH = reinterpret_cast<const short8*>(qAhi);
        const short8* GL = reinterpret_cast<const short8*>(qAlo);
#pragma unroll
        for (int m2 = 0; m2 < 2; ++m2)
#pragma unroll
            for (int ks = 0; ks < 4; ++ks) {
                const int idx = ((p * 2 + m2) * 4 + ks) * 64 + lane;
                Ah[m2][ks] = GH[idx];
                Al[m2][ks] = GL[idx];
            }
    }

    // ---- 4 N-tiles of 16 keys ----
#pragma unroll
    for (int t = 0; t < 4; ++t) {
        const int jl = h * 64 + t * 16 + n;
        const int j = key0 + jl;
        const int jc = (j < NN) ? j : (NN - 1);
        const float* kb = keys + (size_t)jc * DD + quad * 8;

        float4 bv[8];
#pragma unroll
        for (int ks = 0; ks < 4; ++ks) {
            bv[2 * ks]     = *reinterpret_cast<const float4*>(kb + ks * 32);
            bv[2 * ks + 1] = *reinterpret_cast<const float4*>(kb + ks * 32 + 4);
        }

        f32x4 acc[2];
        acc[0] = (f32x4){0.f, 0.f, 0.f, 0.f};
        acc[1] = (f32x4){0.f, 0.f, 0.f, 0.f};
        float ss = 0.f;

#pragma unroll
        for (int ks = 0; ks < 4; ++ks) {
            const float f[8] = {bv[2*ks].x, bv[2*ks].y, bv[2*ks].z, bv[2*ks].w,
                                bv[2*ks+1].x, bv[2*ks+1].y, bv[2*ks+1].z, bv[2*ks+1].w};
            unsigned hw[4], lw[4];
#pragma unroll
            for (int e = 0; e < 4; ++e) {
                const float f0 = f[2 * e], f1 = f[2 * e + 1];
                const unsigned u0 = __float_as_uint(f0), u1 = __float_as_uint(f1);
                hw[e] = __builtin_amdgcn_perm(u1, u0, 0x07060302u);
                const float d0 = f0 - __uint_as_float(u0 & 0xffff0000u);
                const float d1 = f1 - __uint_as_float(u1 & 0xffff0000u);
                lw[e] = __builtin_amdgcn_perm(__float_as_uint(d1), __float_as_uint(d0), 0x07060302u);
                ss = fmaf(f0, f0, fmaf(f1, f1, ss));
            }
            uint4 hv = {hw[0], hw[1], hw[2], hw[3]};
            uint4 lv = {lw[0], lw[1], lw[2], lw[3]};
            short8 Bh = *reinterpret_cast<short8*>(&hv);
            short8 Bl = *reinterpret_cast<short8*>(&lv);
#pragma unroll
            for (int m2 = 0; m2 < 2; ++m2) {
                acc[m2] = __builtin_amdgcn_mfma_f32_16x16x32_bf16(Ah[m2][ks], Bh, acc[m2], 0, 0, 0);
                acc[m2] = __builtin_amdgcn_mfma_f32_16x16x32_bf16(Ah[m2][ks], Bl, acc[m2], 0, 0, 0);
                acc[m2] = __builtin_amdgcn_mfma_f32_16x16x32_bf16(Al[m2][ks], Bh, acc[m2], 0, 0, 0);
            }
        }

        // key norm: lane holds 32 of 128 elems; reduce across quads
        ss += __shfl_xor(ss, 16);
        ss += __shfl_xor(ss, 32);
        const bool valid = (j < NN);
        float scale = 0.f;
        if (valid) scale = imp[j] / fmaxf(sqrtf(ss), 1e-12f);

        // D layout: col = lane&15 (key), row = quad*4 + reg (+ m-tile*16)
#pragma unroll
        for (int m2 = 0; m2 < 2; ++m2)
#pragma unroll
            for (int r = 0; r < 4; ++r) {
                const int row = (p * 2 + m2) * 16 + quad * 4 + r;
                const float v = valid ? acc[m2][r] * scale : -1e30f;
                const unsigned packed = (__float_as_uint(v) & ~0x7Fu) | (unsigned)jl;
                sims[row * 132 + jl] = __uint_as_float(packed);
            }
    }
    __syncthreads();

    // ---- S1: 4 threads/row, each selects top-8 of its 32 keys via sort
    //      networks (4x sort8 + 3x merge8 ~ 280 ops, high ILP). Reads use
    //      R5's proven stagger (2-way banks). Scan order irrelevant: key
    //      identity is packed in the value's low bits.
    float v8[8];
    {
        const int row = tid >> 2, part = tid & 3;
        const float* rp = &sims[row * 132 + part * 32];
        const int st = ((row & 15) + part * 8) & 31;
        float a[8], b[8], c8[8], d8[8];
#pragma unroll
        for (int s = 0; s < 8; ++s) {
            a[s] = rp[(s + st) & 31];
            b[s] = rp[(s + 8 + st) & 31];
        }
        sort8(a); sort8(b);
        merge8(a, b, c8);
#pragma unroll
        for (int s = 0; s < 8; ++s) {
            a[s] = rp[(s + 16 + st) & 31];
            b[s] = rp[(s + 24 + st) & 31];
        }
        sort8(a); sort8(b);
        merge8(a, b, d8);
        merge8(c8, d8, v8);
    }
    __syncthreads();   // all S1 reads complete; sims region reusable

    // ---- write sorted partial lists, +row rotation: S2 reads land on bank
    //      (5*row + c) & 31 with 5 odd -> exactly 2-way (free).
    {
        const int row = tid >> 2, part = tid & 3;
#pragma unroll
        for (int s = 0; s < 8; ++s)
            sims[row * 132 + ((part * 8 + s + row) & 31)] = v8[s];
    }
    __syncthreads();

    // ---- S2: 1 thread/row, valley-merge 4 sorted lists -> top-8, write ----
    if (tid < 64) {
        const int row = tid;
        const float* rp = &sims[row * 132];
        float l0[8], l1[8], l2[8], l3[8];
#pragma unroll
        for (int s = 0; s < 8; ++s) {
            l0[s] = rp[(s + row) & 31];
            l1[s] = rp[(8 + s + row) & 31];
            l2[s] = rp[(16 + s + row) & 31];
            l3[s] = rp[(24 + s + row) & 31];
        }
        float m01[8], m23[8], m8[8];
        merge8(l0, l1, m01);
        merge8(l2, l3, m23);
        merge8(m01, m23, m8);
        float4* out4 = reinterpret_cast<float4*>(cand_v + (size_t)row * CPB + (size_t)blk * KK);
        out4[0] = (float4){m8[0], m8[1], m8[2], m8[3]};
        out4[1] = (float4){m8[4], m8[5], m8[6], m8[7]};
    }
}

// ---------------- Kernel CD: per-row candidate merge + attention + W_comb -----
__global__ __launch_bounds__(256) void mergefinish_kernel(
    const float* __restrict__ cand_v,  // [64][CPB] packed floats
    const float* __restrict__ values,  // [N][128]
    const float* __restrict__ w_attn,  // [128]
    const float* __restrict__ b_attn,  // [1]
    const float* __restrict__ W_comb,  // [128][128]
    const float* __restrict__ b_comb,  // [128]
    float* __restrict__ out)           // [64][128]
{
    __shared__ float lv[256 * 8];
    __shared__ int   li[256 * 8];
    __shared__ int   tk[KK];
    __shared__ float red[KK][DD];
    __shared__ float tvals[KK];
    __shared__ float mem[DD];

    const int tid = threadIdx.x;
    const int row = blockIdx.x;

    // P1: 256 threads scan the row's 6256 candidates (float4, coalesced)
    {
        float v8[8]; int i8[8];
#pragma unroll
        for (int s = 0; s < 8; ++s) { v8[s] = -1e30f; i8[s] = 0; }
        const float4* cv4 = reinterpret_cast<const float4*>(cand_v + (size_t)row * CPB);
        for (int c4 = tid; c4 < CPB / 4; c4 += 256) {
            const float4 v = cv4[c4];
            const int c = c4 * 4;
            bpins8(v.x, c + 0, v8, i8);
            bpins8(v.y, c + 1, v8, i8);
            bpins8(v.z, c + 2, v8, i8);
            bpins8(v.w, c + 3, v8, i8);
        }
#pragma unroll
        for (int s = 0; s < 8; ++s) { lv[tid * 8 + s] = v8[s]; li[tid * 8 + s] = i8[s]; }
    }
    __syncthreads();

    // P2: wave 0 reduces 256 lists -> 64 lists -> top-8 via head extraction.
    // Candidate position c decodes to key idx: (c>>3)*CHUNK + (bits(v)&127).
    if (tid < 64) {
        float m8[8]; int mi8[8];
#pragma unroll
        for (int s = 0; s < 8; ++s) { m8[s] = -1e30f; mi8[s] = 0; }
        for (int k2 = 0; k2 < 4; ++k2)
#pragma unroll
            for (int s = 0; s < 8; ++s)
                bpins8(lv[(tid + 64 * k2) * 8 + s], li[(tid + 64 * k2) * 8 + s], m8, mi8);
        for (int rd = 0; rd < KK; ++rd) {
            float m = m8[0];
#pragma unroll
            for (int d = 1; d < 64; d <<= 1) m = fmaxf(m, __shfl_xor(m, d));
            const unsigned long long msk = __ballot(m8[0] == m);
            const int wl = (int)(__ffsll((long long)msk) - 1);
            const int wc = __shfl(mi8[0], wl);
            if (tid == 0)
                tk[rd] = (wc >> 3) * CHUNK + (int)(__float_as_uint(m) & 127u);
            if (tid == wl) {
#pragma unroll
                for (int s = 0; s < 7; ++s) { m8[s] = m8[s + 1]; mi8[s] = mi8[s + 1]; }
                m8[7] = -1e30f;
            }
        }
    }
    __syncthreads();

    // D phase: gather + softmax attention + W_comb (threads 0..127 active)
    float vk[KK];
    if (tid < 128) {
#pragma unroll
        for (int k = 0; k < KK; ++k)
            vk[k] = values[(size_t)tk[k] * DD + tid];
        const float wa = w_attn[tid];
#pragma unroll
        for (int k = 0; k < KK; ++k) red[k][tid] = vk[k] * wa;
    }
    __syncthreads();
    if (tid < KK) {
        float s = 0.f;
        for (int i = 0; i < DD; ++i) s += red[tid][i];
        tvals[tid] = s + b_attn[0];
    }
    __syncthreads();
    if (tid < 128) {
        float m = tvals[0];
#pragma unroll
        for (int k = 1; k < KK; ++k) m = fmaxf(m, tvals[k]);
        float e[KK]; float se = 0.f;
#pragma unroll
        for (int k = 0; k < KK; ++k) { e[k] = expf(tvals[k] - m); se += e[k]; }
        const float inv = 1.f / se;
        float md = 0.f;
#pragma unroll
        for (int k = 0; k < KK; ++k) md += (e[k] * inv) * vk[k];
        mem[tid] = md;
    }
    __syncthreads();
    if (tid < 128) {
        float acc = b_comb[tid];
        const float4* wrow = reinterpret_cast<const float4*>(W_comb + (size_t)tid * DD);
#pragma unroll 8
        for (int c = 0; c < DD / 4; ++c) {
            float4 wv = wrow[c];
            acc = fmaf(wv.x, mem[c * 4 + 0], acc);
            acc = fmaf(wv.y, mem[c * 4 + 1], acc);
            acc = fmaf(wv.z, mem[c * 4 + 2], acc);
            acc = fmaf(wv.w, mem[c * 4 + 3], acc);
        }
        out[row * DD + tid] = acc;
    }
}

extern "C" void kernel_launch(void* const* d_in, const int* in_sizes, int n_in,
                              void* d_out, int out_size, void* d_ws, size_t ws_size,
                              hipStream_t stream) {
    const float* query  = (const float*)d_in[0];
    const float* keys   = (const float*)d_in[1];
    const float* values = (const float*)d_in[2];
    const float* imp    = (const float*)d_in[3];
    const float* Wq     = (const float*)d_in[4];
    const float* bq     = (const float*)d_in[5];
    const float* wattn  = (const float*)d_in[6];
    const float* battn  = (const float*)d_in[7];
    const float* Wcomb  = (const float*)d_in[8];
    const float* bcomb  = (const float*)d_in[9];

    unsigned short* qAhi = (unsigned short*)d_ws;          // 8192 ushort (16 KB)
    unsigned short* qAlo = qAhi + 8192;                    // 8192 ushort (16 KB)
    float* cand_v = (float*)(qAlo + 8192);                 // 64*CPB floats (1.6 MB)

    qproj_kernel<<<BB, 128, 0, stream>>>(query, Wq, bq, qAhi, qAlo);
    simtopk_kernel<<<NBLK, 256, 0, stream>>>(qAhi, qAlo, keys, imp, cand_v);
    mergefinish_kernel<<<BB, 256, 0, stream>>>(cand_v, values, wattn, battn,
                                               Wcomb, bcomb, (float*)d_out);
}